// Round 23
// baseline (291.123 us; speedup 1.0000x reference)
//
#include <hip/hip_runtime.h>
#include <hip/hip_bf16.h>

#define IN_F 128
#define HF 256
#define BN_EPS 1e-5f
#define SELU_SCALE 1.0507009873554805f
#define SELU_ALPHA 1.6732632423543772f

typedef __attribute__((ext_vector_type(8))) _Float16 half8;
typedef __attribute__((ext_vector_type(8))) unsigned short ushort8;
typedef __attribute__((ext_vector_type(2))) unsigned int u32x2;
typedef __attribute__((ext_vector_type(4))) unsigned int u32x4;
typedef __attribute__((ext_vector_type(4))) float f32x4;

__device__ __forceinline__ short f2h(float f) {
    _Float16 h = (_Float16)f;               // RTNE fp32->fp16
    return __builtin_bit_cast(short, h);
}

// fast SELU: native v_exp_f32
__device__ __forceinline__ float selu_f(float x) {
    const float SA = SELU_SCALE * SELU_ALPHA;
    float e = __expf(x);
    return x > 0.f ? SELU_SCALE * x : SA * e - SA;
}

// pack 2 fp32 -> 2 fp16 (RTZ), one instruction
__device__ __forceinline__ unsigned int pk2h(float a, float b) {
    return __builtin_bit_cast(unsigned int, __builtin_amdgcn_cvt_pkrtz(a, b));
}

__device__ __forceinline__ float h2f(unsigned short u) {
    return (float)__builtin_bit_cast(_Float16, u);
}

// async global->LDS, 16B/lane; LDS dest MUST be wave-uniform (lane*16 implicit)
__device__ __forceinline__ void gld_lds16(const void* g, void* l) {
    __builtin_amdgcn_global_load_lds(
        (const __attribute__((address_space(1))) unsigned int*)g,
        (__attribute__((address_space(3))) unsigned int*)l, 16, 0, 0);
}

// Fold BN into weights.
// Wf[s(24)][nb(4)][kc(4)][n64(64)][j(8)] fp16 (wave-private slices; s=layer*8+kk).
// ALSO WyF (layer0 only) fragment-linear: WyF[w(8)][kk(4)][ni(4)][lane(64)][j(8)],
// Y-col = w*64+ni*16+(lane&15), k' = kk*32+(lane>>4)*8+j; cols<256 = dst half,
// cols>=256 = src half. bf loads = lane*16B coalesced.
__global__ void prep_kernel(const float* __restrict__ W0, const float* __restrict__ b0,
                            const float* __restrict__ g0, const float* __restrict__ beta0,
                            const float* __restrict__ m0, const float* __restrict__ v0,
                            const float* __restrict__ Ws, const float* __restrict__ bs,
                            const float* __restrict__ gs, const float* __restrict__ betas,
                            const float* __restrict__ ms, const float* __restrict__ vs,
                            unsigned short* __restrict__ Wf, unsigned short* __restrict__ WyF,
                            float* __restrict__ biasArr) {
    int b = blockIdx.x;
    int layer = b >> 8;
    int n = b & 255;
    int k = threadIdx.x;
    const float *W, *bb, *g, *be, *m, *v;
    if (layer == 0) { W = W0; bb = b0; g = g0; be = beta0; m = m0; v = v0; }
    else {
        int i = layer - 1;
        W = Ws + (size_t)i * HF * HF; bb = bs + i * HF; g = gs + i * HF;
        be = betas + i * HF; m = ms + i * HF; v = vs + i * HF;
    }
    float s = g[n] * rsqrtf(v[n] + BN_EPS);
    unsigned short hv = (unsigned short)f2h(W[n * HF + k] * s);
    int kk = k >> 5, kc = (k >> 3) & 3, j = k & 7;
    int sIdx = layer * 8 + kk, nb = n >> 6, n64 = n & 63;
    Wf[((((size_t)sIdx * 4 + nb) * 4 + kc) * 64 + n64) * 8 + j] = hv;
    if (layer == 0) {
        int col = (k < 128) ? n : (HF + n);
        int kp = k & 127;
        int w = col >> 6, c64 = col & 63;
        int ni = c64 >> 4, lr = c64 & 15;
        int ykk = kp >> 5, lg = (kp >> 3) & 3, yj = kp & 7;
        WyF[((((size_t)w * 4 + ykk) * 4 + ni) * 64 + (lg * 16 + lr)) * 8 + yj] = hv;
    }
    if (k == 0) biasArr[layer * HF + n] = (bb[n] - m[n]) * s + be[n];
}

__global__ void count_kernel(const int* __restrict__ dstI, int* __restrict__ cnt, int E) {
    int i = blockIdx.x * 256 + threadIdx.x;
    if (i < E) atomicAdd(cnt + dstI[i], 1);
}

// 3-phase parallel exclusive scan of cnt -> wrk; ALSO overwrites cnt[i] with
// float 1/max(cnt,1) (the mean divisor, consumed by the fused epilogue).
__global__ void scan_local(int* __restrict__ cnt, int* __restrict__ wrk,
                           int* __restrict__ btot, int n) {
    __shared__ int s[1024];
    int b = blockIdx.x, t = threadIdx.x, i = b * 1024 + t;
    int v = (i < n) ? cnt[i] : 0;
    s[t] = v;
    __syncthreads();
#pragma unroll
    for (int d = 1; d < 1024; d <<= 1) {
        int add = (t >= d) ? s[t - d] : 0;
        __syncthreads();
        s[t] += add;
        __syncthreads();
    }
    if (i < n) {
        wrk[i] = s[t] - v;
        ((float*)cnt)[i] = 1.f / fmaxf((float)v, 1.f);   // inv-count, in place
    }
    if (t == 1023) btot[b] = s[1023];
}
__global__ void scan_tops(int* __restrict__ btot, int nb) {
    if (threadIdx.x == 0) {
        int run = 0;
        for (int i = 0; i < nb; ++i) { int v = btot[i]; btot[i] = run; run += v; }
    }
}
__global__ void scan_add(int* __restrict__ wrk, const int* __restrict__ btot, int n) {
    int i = blockIdx.x * 1024 + threadIdx.x;
    if (i < n) wrk[i] += btot[blockIdx.x];
}

// perm[pos] = original edge id, grouped by dst (counting sort)
__global__ void scatter_kernel(const int* __restrict__ dstI, int* __restrict__ wrk,
                               int* __restrict__ perm, int E) {
    int i = blockIdx.x * 256 + threadIdx.x;
    if (i < E) {
        int p = atomicAdd(wrk + dstI[i], 1);
        perm[p] = i;
    }
}

// Y-precompute: Y[n][512] fp16 = [Wy_dst @ x[n] | Wy_src @ x[n]].
// Block = 64 nodes; 512 thr = 8 waves; wave w = 64 nodes x cols w*64..+63.
// NO LDS, NO BARRIERS: af built directly from global x (L2/L3-hot) with inline
// cvt_pkrtz; bf from fragment-linear WyF (coalesced 1KB wave reads). Pure ILP
// chain -> compiler software-pipelines; per-block serial latency minimized.
// Swapped mfma -> lane&15=node, reg-dim=col -> direct u32x2 stores.
__global__ __launch_bounds__(512)
void y_kernel(const float* __restrict__ x, const unsigned short* __restrict__ WyF,
              unsigned short* __restrict__ y16, int Nn) {
    const int base = blockIdx.x * 64;
    const int t = threadIdx.x;
    const int lane = t & 63;
    const int w = t >> 6;
    const int lrow = lane & 15;
    const int lgrp = lane >> 4;

    f32x4 acc[4][4];
    const f32x4 zero = {0.f, 0.f, 0.f, 0.f};
#pragma unroll
    for (int mi = 0; mi < 4; ++mi)
#pragma unroll
        for (int ni = 0; ni < 4; ++ni) acc[mi][ni] = zero;

#pragma unroll
    for (int kk = 0; kk < 4; ++kk) {      // K=128 in 4 slices of 32
        half8 af[4], bf[4];
#pragma unroll
        for (int mi = 0; mi < 4; ++mi) {
            int node = base + mi * 16 + lrow;
            int nc = node < Nn ? node : Nn - 1;          // clamp (guarded at store)
            const float* xr = x + (size_t)nc * IN_F + kk * 32 + lgrp * 8;
            f32x4 v0 = *(const f32x4*)xr;
            f32x4 v1 = *(const f32x4*)(xr + 4);
            u32x4 u;
            u[0] = pk2h(v0[0], v0[1]); u[1] = pk2h(v0[2], v0[3]);
            u[2] = pk2h(v1[0], v1[1]); u[3] = pk2h(v1[2], v1[3]);
            af[mi] = __builtin_bit_cast(half8, u);
        }
#pragma unroll
        for (int ni = 0; ni < 4; ++ni)
            bf[ni] = *(const half8*)(WyF +
                ((((size_t)w * 4 + kk) * 4 + ni) * 64 + lane) * 8);   // coalesced
#pragma unroll
        for (int mi = 0; mi < 4; ++mi)
#pragma unroll
            for (int ni = 0; ni < 4; ++ni)
                acc[mi][ni] = __builtin_amdgcn_mfma_f32_16x16x32_f16(
                    bf[ni], af[mi], acc[mi][ni], 0, 0, 0);   // swapped: lane&15=node
    }

#pragma unroll
    for (int mi = 0; mi < 4; ++mi) {
        int node = base + mi * 16 + lrow;
        if (node < Nn) {
#pragma unroll
            for (int ni = 0; ni < 4; ++ni) {
                int col = w * 64 + ni * 16 + lgrp * 4;
                u32x2 d = {pk2h(acc[mi][ni][0], acc[mi][ni][1]),
                           pk2h(acc[mi][ni][2], acc[mi][ni][3])};
                *(u32x2*)(y16 + (size_t)node * 512 + col) = d;
            }
        }
    }
}

// ===================== Y-path fused kernel (layers 2,3) =====================
// Layer 1 collapsed to gather-add: A_act row = selu(Ya[dst]+Yb[src]+b0).
// Then 2 MFMA layers (16 wave-private k-steps, barrier-free loop as R20).
__global__ __launch_bounds__(256, 3)
void fused_kernelY(const unsigned short* __restrict__ y16,
                   const int* __restrict__ dstI, const int* __restrict__ srcI,
                   const int* __restrict__ perm,
                   const unsigned char* __restrict__ Wfb,
                   const float* __restrict__ biasArr,
                   const float* __restrict__ invA,
                   unsigned char* __restrict__ hB, float* __restrict__ agg) {
    __shared__ __align__(16) unsigned char lds[49152];
    __shared__ int peL[64];
    __shared__ int pdL[64];

    const int base = blockIdx.x * 64;
    const int t = threadIdx.x;
    const int lane = t & 63;
    const int w = t >> 6;
    const int lrow = lane & 15;
    const int lgrp = lane >> 4;
    unsigned char* mySlice = lds + 32768 + w * 4096;

    auto stageB = [&](int sGlob) {        // global slice 8..23
        const unsigned char* src = Wfb + ((size_t)sGlob << 14) + (w << 12);
#pragma unroll
        for (int i = 0; i < 4; ++i)
            gld_lds16(src + (i * 64 + lane) * 16, mySlice + i * 1024);
    };
    auto readA = [&](int kk, int mi) -> half8 {
        int row = mi * 16 + lrow;
        return *(const half8*)&lds[row * 512 +
            ((kk * 64 + lgrp * 16) ^ ((row & 7) << 4))];
    };

    stageB(8);   // first slice of layer 2

    // ---- layer-1 fill: A_act row r = selu(Ya[dst]+Yb[src]+b0), swizzled fp16 ----
    {
        int r = t >> 2, q = t & 3;                 // sorted row, col-quarter (64 cols)
        int e = perm[base + r];
        int d = dstI[e], si = srcI[e];
        const ushort8* Ja = (const ushort8*)(y16 + (size_t)d * 512 + q * 64);
        const ushort8* Jb = (const ushort8*)(y16 + (size_t)si * 512 + 256 + q * 64);
        const float* bp = biasArr + q * 64;
        int swz = (r & 7) << 4;
#pragma unroll
        for (int u = 0; u < 8; ++u) {
            ushort8 a8 = Ja[u];
            ushort8 b8 = Jb[u];
            f32x4 bv0 = *(const f32x4*)(bp + u * 8);
            f32x4 bv1 = *(const f32x4*)(bp + u * 8 + 4);
            float vv[8];
#pragma unroll
            for (int j = 0; j < 4; ++j)
                vv[j] = selu_f(h2f(a8[j]) + h2f(b8[j]) + bv0[j]);
#pragma unroll
            for (int j = 0; j < 4; ++j)
                vv[4 + j] = selu_f(h2f(a8[4 + j]) + h2f(b8[4 + j]) + bv1[j]);
            unsigned int p0 = pk2h(vv[0], vv[1]), p1 = pk2h(vv[2], vv[3]);
            unsigned int p2 = pk2h(vv[4], vv[5]), p3 = pk2h(vv[6], vv[7]);
            u32x2 w0 = {p0, p1}, w1 = {p2, p3};
            int byteOff = r * 512 + ((q * 128 + u * 16) ^ swz);
            *(u32x2*)&lds[byteOff] = w0;
            *(u32x2*)&lds[byteOff + 8] = w1;
        }
    }
    __syncthreads();   // A_act visible

    f32x4 acc[4][4];
    const f32x4 zero = {0.f, 0.f, 0.f, 0.f};

#pragma unroll
    for (int LL = 0; LL < 2; ++LL) {      // LL=0: layer 2 (swapped); LL=1: layer 3
#pragma unroll
        for (int mi = 0; mi < 4; ++mi)
#pragma unroll
            for (int ni = 0; ni < 4; ++ni) acc[mi][ni] = zero;

        half8 af_c[4], af_n[4];
#pragma unroll
        for (int kk = 0; kk < 8; ++kk) {
            const int sl = LL * 8 + kk;   // local step 0..15

            asm volatile("s_waitcnt vmcnt(0)" ::: "memory");
            __builtin_amdgcn_sched_barrier(0);

            if (kk == 0) {
#pragma unroll
                for (int mi = 0; mi < 4; ++mi) af_c[mi] = readA(0, mi);
            }
            half8 bf[4];
#pragma unroll
            for (int ni = 0; ni < 4; ++ni)
                bf[ni] = *(const half8*)&mySlice[lgrp * 1024 + (ni * 16 + lrow) * 16];
            asm volatile("s_waitcnt lgkmcnt(0)" ::: "memory");
            __builtin_amdgcn_sched_barrier(0);

            if (sl + 1 < 16) stageB(8 + sl + 1);

            if (kk < 7) {
#pragma unroll
                for (int mi = 0; mi < 4; ++mi) af_n[mi] = readA(kk + 1, mi);
            }

            if (LL < 1) {
#pragma unroll
                for (int mi = 0; mi < 4; ++mi)
#pragma unroll
                    for (int ni = 0; ni < 4; ++ni)
                        acc[mi][ni] = __builtin_amdgcn_mfma_f32_16x16x32_f16(
                            bf[ni], af_c[mi], acc[mi][ni], 0, 0, 0);
            } else {
#pragma unroll
                for (int mi = 0; mi < 4; ++mi)
#pragma unroll
                    for (int ni = 0; ni < 4; ++ni)
                        acc[mi][ni] = __builtin_amdgcn_mfma_f32_16x16x32_f16(
                            af_c[mi], bf[ni], acc[mi][ni], 0, 0, 0);
            }
            if (kk < 7) {
#pragma unroll
                for (int mi = 0; mi < 4; ++mi) af_c[mi] = af_n[mi];
            }
        }

        if (LL < 1) {
            // ---- handoff (swapped layout), bias layer 1 ----
            __syncthreads();
#pragma unroll
            for (int ni = 0; ni < 4; ++ni) {
                f32x4 bv = *(const f32x4*)(biasArr + HF + w * 64 + ni * 16 + lgrp * 4);
#pragma unroll
                for (int mi = 0; mi < 4; ++mi) {
                    int row = mi * 16 + lrow;
                    float v0 = selu_f(acc[mi][ni][0] + bv[0]);
                    float v1 = selu_f(acc[mi][ni][1] + bv[1]);
                    float v2 = selu_f(acc[mi][ni][2] + bv[2]);
                    float v3 = selu_f(acc[mi][ni][3] + bv[3]);
                    u32x2 d = {pk2h(v0, v1), pk2h(v2, v3)};
                    *(u32x2*)&lds[row * 512 +
                        ((w * 128 + ni * 32 + lgrp * 8) ^ ((row & 7) << 4))] = d;
                }
            }
            __syncthreads();
        } else {
            // ---- epilogue: bias layer 2; segment-sum scatter-mean ----
            __syncthreads();
            if (t < 64) {
                int e = perm[base + t];
                peL[t] = e;
                pdL[t] = dstI[e];
            }
            float bc[4];
#pragma unroll
            for (int ni = 0; ni < 4; ++ni) bc[ni] = biasArr[2 * HF + w * 64 + ni * 16 + lrow];
            unsigned char* EP = lds + 32768;
            int curD = -1;
            float carry = 0.f;
#pragma unroll
            for (int cc = 0; cc < 4; ++cc) {
                if (cc) __syncthreads();
#pragma unroll
                for (int ni = 0; ni < 4; ++ni)
#pragma unroll
                    for (int r = 0; r < 4; ++r) {
                        int er = lgrp * 4 + r;
                        int cg = w * 64 + ni * 16 + lrow;
                        float val = selu_f(acc[cc][ni][r] + bc[ni]);
                        *(float*)&EP[er * 1024 + ((cg * 4) ^ ((er & 7) << 4))] = val;
                    }
                __syncthreads();
#pragma unroll
                for (int i = 0; i < 4; ++i) {
                    int f = t + i * 256;
                    int row = f >> 6, ch = f & 63;
                    f32x4 v = *(const f32x4*)&EP[row * 1024 + ((ch * 16) ^ ((row & 7) << 4))];
                    *(f32x4*)(hB + (size_t)peL[cc * 16 + row] * 1024 + ch * 16) = v;
                }
#pragma unroll
                for (int r = 0; r < 16; ++r) {
                    float v = *(const float*)&EP[r * 1024 + ((t * 4) ^ ((r & 7) << 4))];
                    int d = pdL[cc * 16 + r];
                    if (d != curD) {
                        if (curD >= 0)
                            atomicAdd(agg + (size_t)curD * HF + t, carry * invA[curD]);
                        carry = 0.f;
                        curD = d;
                    }
                    carry += v;
                }
            }
            atomicAdd(agg + (size_t)curD * HF + t, carry * invA[curD]);
        }
    }
}

// ===================== fallback: R20 3-layer fused kernel =====================
__global__ __launch_bounds__(256, 3)
void fused_old(const float* __restrict__ x,
               const int* __restrict__ dstI, const int* __restrict__ srcI,
               const int* __restrict__ perm,
               const unsigned char* __restrict__ Wfb,
               const float* __restrict__ biasArr,
               const float* __restrict__ invA,
               unsigned char* __restrict__ hB, float* __restrict__ agg) {
    __shared__ __align__(16) unsigned char lds[49152];
    __shared__ int peL[64];
    __shared__ int pdL[64];

    const int base = blockIdx.x * 64;
    const int t = threadIdx.x;
    const int lane = t & 63;
    const int w = t >> 6;
    const int lrow = lane & 15;
    const int lgrp = lane >> 4;
    unsigned char* mySlice = lds + 32768 + w * 4096;

    auto stageB = [&](int s) {
        const unsigned char* src = Wfb + ((size_t)s << 14) + (w << 12);
#pragma unroll
        for (int i = 0; i < 4; ++i)
            gld_lds16(src + (i * 64 + lane) * 16, mySlice + i * 1024);
    };
    auto readA = [&](int kk, int mi) -> half8 {
        int row = mi * 16 + lrow;
        return *(const half8*)&lds[row * 512 +
            ((kk * 64 + lgrp * 16) ^ ((row & 7) << 4))];
    };

    stageB(0);
    {
        int r = t >> 2, q = t & 3;
        int e = perm[base + r];
        int idx = (q < 2 ? dstI : srcI)[e];
        const float* xr = x + (size_t)idx * IN_F + (q & 1) * 64;
        int swz = (r & 7) << 4;
#pragma unroll
        for (int u = 0; u < 16; ++u) {
            f32x4 v = *(const f32x4*)(xr + u * 4);
            u32x2 hv = {pk2h(v[0], v[1]), pk2h(v[2], v[3])};
            *(u32x2*)&lds[r * 512 + ((q * 128 + u * 8) ^ swz)] = hv;
        }
    }
    __syncthreads();

    f32x4 acc[4][4];
    const f32x4 zero = {0.f, 0.f, 0.f, 0.f};

#pragma unroll
    for (int L = 0; L < 3; ++L) {
#pragma unroll
        for (int mi = 0; mi < 4; ++mi)
#pragma unroll
            for (int ni = 0; ni < 4; ++ni) acc[mi][ni] = zero;

        half8 af_c[4], af_n[4];
#pragma unroll
        for (int kk = 0; kk < 8; ++kk) {
            const int s = L * 8 + kk;
            asm volatile("s_waitcnt vmcnt(0)" ::: "memory");
            __builtin_amdgcn_sched_barrier(0);
            if (kk == 0) {
#pragma unroll
                for (int mi = 0; mi < 4; ++mi) af_c[mi] = readA(0, mi);
            }
            half8 bf[4];
#pragma unroll
            for (int ni = 0; ni < 4; ++ni)
                bf[ni] = *(const half8*)&mySlice[lgrp * 1024 + (ni * 16 + lrow) * 16];
            asm volatile("s_waitcnt lgkmcnt(0)" ::: "memory");
            __builtin_amdgcn_sched_barrier(0);
            if (s + 1 < 24) stageB(s + 1);
            if (kk < 7) {
#pragma unroll
                for (int mi = 0; mi < 4; ++mi) af_n[mi] = readA(kk + 1, mi);
            }
            if (L < 2) {
#pragma unroll
                for (int mi = 0; mi < 4; ++mi)
#pragma unroll
                    for (int ni = 0; ni < 4; ++ni)
                        acc[mi][ni] = __builtin_amdgcn_mfma_f32_16x16x32_f16(
                            bf[ni], af_c[mi], acc[mi][ni], 0, 0, 0);
            } else {
#pragma unroll
                for (int mi = 0; mi < 4; ++mi)
#pragma unroll
                    for (int ni = 0; ni < 4; ++ni)
                        acc[mi][ni] = __builtin_amdgcn_mfma_f32_16x16x32_f16(
                            af_c[mi], bf[ni], acc[mi][ni], 0, 0, 0);
            }
            if (kk < 7) {
#pragma unroll
                for (int mi = 0; mi < 4; ++mi) af_c[mi] = af_n[mi];
            }
        }

        if (L < 2) {
            __syncthreads();
#pragma unroll
            for (int ni = 0; ni < 4; ++ni) {
                f32x4 bv = *(const f32x4*)(biasArr + L * HF + w * 64 + ni * 16 + lgrp * 4);
#pragma unroll
                for (int mi = 0; mi < 4; ++mi) {
                    int row = mi * 16 + lrow;
                    float v0 = selu_f(acc[mi][ni][0] + bv[0]);
                    float v1 = selu_f(acc[mi][ni][1] + bv[1]);
                    float v2 = selu_f(acc[mi][ni][2] + bv[2]);
                    float v3 = selu_f(acc[mi][ni][3] + bv[3]);
                    u32x2 d = {pk2h(v0, v1), pk2h(v2, v3)};
                    *(u32x2*)&lds[row * 512 +
                        ((w * 128 + ni * 32 + lgrp * 8) ^ ((row & 7) << 4))] = d;
                }
            }
            __syncthreads();
        } else {
            __syncthreads();
            if (t < 64) {
                int e = perm[base + t];
                peL[t] = e;
                pdL[t] = dstI[e];
            }
            float bc[4];
#pragma unroll
            for (int ni = 0; ni < 4; ++ni) bc[ni] = biasArr[2 * HF + w * 64 + ni * 16 + lrow];
            unsigned char* EP = lds + 32768;
            int curD = -1;
            float carry = 0.f;
#pragma unroll
            for (int cc = 0; cc < 4; ++cc) {
                if (cc) __syncthreads();
#pragma unroll
                for (int ni = 0; ni < 4; ++ni)
#pragma unroll
                    for (int r = 0; r < 4; ++r) {
                        int er = lgrp * 4 + r;
                        int cg = w * 64 + ni * 16 + lrow;
                        float val = selu_f(acc[cc][ni][r] + bc[ni]);
                        *(float*)&EP[er * 1024 + ((cg * 4) ^ ((er & 7) << 4))] = val;
                    }
                __syncthreads();
#pragma unroll
                for (int i = 0; i < 4; ++i) {
                    int f = t + i * 256;
                    int row = f >> 6, ch = f & 63;
                    f32x4 v = *(const f32x4*)&EP[row * 1024 + ((ch * 16) ^ ((row & 7) << 4))];
                    *(f32x4*)(hB + (size_t)peL[cc * 16 + row] * 1024 + ch * 16) = v;
                }
#pragma unroll
                for (int r = 0; r < 16; ++r) {
                    float v = *(const float*)&EP[r * 1024 + ((t * 4) ^ ((r & 7) << 4))];
                    int d = pdL[cc * 16 + r];
                    if (d != curD) {
                        if (curD >= 0)
                            atomicAdd(agg + (size_t)curD * HF + t, carry * invA[curD]);
                        carry = 0.f;
                        curD = d;
                    }
                    carry += v;
                }
            }
            atomicAdd(agg + (size_t)curD * HF + t, carry * invA[curD]);
        }
    }
}

extern "C" void kernel_launch(void* const* d_in, const int* in_sizes, int n_in,
                              void* d_out, int out_size, void* d_ws, size_t ws_size,
                              hipStream_t stream) {
    const float* x     = (const float*)d_in[0];
    const int*   ei    = (const int*)d_in[1];
    const float* W0    = (const float*)d_in[2];
    const float* b0    = (const float*)d_in[3];
    const float* g0    = (const float*)d_in[4];
    const float* beta0 = (const float*)d_in[5];
    const float* m0    = (const float*)d_in[6];
    const float* v0    = (const float*)d_in[7];
    const float* Ws    = (const float*)d_in[8];
    const float* bs    = (const float*)d_in[9];
    const float* gs    = (const float*)d_in[10];
    const float* betas = (const float*)d_in[11];
    const float* ms    = (const float*)d_in[12];
    const float* vs    = (const float*)d_in[13];

    const int Nn = in_sizes[0] / IN_F;   // 20000
    const int E  = in_sizes[1] / 2;      // 320000

    float* agg  = (float*)d_out;
    float* hptr = agg + (size_t)Nn * HF;   // final h region of d_out

    // ws layout: Wf 384KB | WyF 128KB | bias 3KB | cnt 80KB | wrk 80KB | perm 1.25MB | Y 20.5MB
    char* wsb = (char*)d_ws;
    unsigned short* Wf = (unsigned short*)wsb;                      // @0, 393216 B
    unsigned short* WyF = (unsigned short*)(wsb + 393216);          // 131072 B
    float* biasArr = (float*)(wsb + 524288);                        // 3072 B
    int* cnt  = (int*)(wsb + 527360);                               // 80000 B (becomes inv f32)
    int* wrk  = (int*)(wsb + 607360);                               // 80000 B
    int* perm = (int*)(wsb + 687360);                               // 1280000 B
    unsigned short* y16 = (unsigned short*)(wsb + 2097152);         // 20480000 B
    int* btot = (int*)agg;            // scratch: agg region, re-zeroed below

    const size_t WS_NEED = 2097152ull + (size_t)Nn * 512 * 2;
    const bool useY = (ws_size >= WS_NEED);

    const int* srcI = ei;        // edge_index[0]
    const int* dstI = ei + E;    // edge_index[1]

    const int nScan = (Nn + 1023) / 1024;   // 20

    prep_kernel<<<3 * HF, HF, 0, stream>>>(W0, b0, g0, beta0, m0, v0,
                                           Ws, bs, gs, betas, ms, vs, Wf, WyF, biasArr);
    if (useY)
        y_kernel<<<(Nn + 63) / 64, 512, 0, stream>>>(x, WyF, y16, Nn);
    hipMemsetAsync(cnt, 0, (size_t)Nn * sizeof(int), stream);
    count_kernel<<<(E + 255) / 256, 256, 0, stream>>>(dstI, cnt, E);
    scan_local<<<nScan, 1024, 0, stream>>>(cnt, wrk, btot, Nn);   // also cnt -> inv
    scan_tops<<<1, 64, 0, stream>>>(btot, nScan);
    scan_add<<<nScan, 1024, 0, stream>>>(wrk, btot, Nn);
    hipMemsetAsync(agg, 0, (size_t)Nn * HF * sizeof(float), stream);  // clears btot too
    scatter_kernel<<<(E + 255) / 256, 256, 0, stream>>>(dstI, wrk, perm, E);

    if (useY)
        fused_kernelY<<<E / 64, 256, 0, stream>>>(y16, dstI, srcI, perm,
                                                  (const unsigned char*)Wf, biasArr,
                                                  (const float*)cnt,
                                                  (unsigned char*)hptr, agg);
    else
        fused_old<<<E / 64, 256, 0, stream>>>(x, dstI, srcI, perm,
                                              (const unsigned char*)Wf, biasArr,
                                              (const float*)cnt,
                                              (unsigned char*)hptr, agg);
}

// Round 24
// 268.155 us; speedup vs baseline: 1.0857x; 1.0857x over previous
//
#include <hip/hip_runtime.h>
#include <hip/hip_bf16.h>

#define IN_F 128
#define HF 256
#define BN_EPS 1e-5f
#define SELU_SCALE 1.0507009873554805f
#define SELU_ALPHA 1.6732632423543772f

typedef __attribute__((ext_vector_type(8))) _Float16 half8;
typedef __attribute__((ext_vector_type(2))) unsigned int u32x2;
typedef __attribute__((ext_vector_type(4))) float f32x4;

__device__ __forceinline__ short f2h(float f) {
    _Float16 h = (_Float16)f;               // RTNE fp32->fp16
    return __builtin_bit_cast(short, h);
}

// fast SELU: native v_exp_f32
__device__ __forceinline__ float selu_f(float x) {
    const float SA = SELU_SCALE * SELU_ALPHA;
    float e = __expf(x);
    return x > 0.f ? SELU_SCALE * x : SA * e - SA;
}

// pack 2 fp32 -> 2 fp16 (RTZ), one instruction
__device__ __forceinline__ unsigned int pk2h(float a, float b) {
    return __builtin_bit_cast(unsigned int, __builtin_amdgcn_cvt_pkrtz(a, b));
}

// async global->LDS, 16B/lane; LDS dest MUST be wave-uniform (lane*16 implicit)
__device__ __forceinline__ void gld_lds16(const void* g, void* l) {
    __builtin_amdgcn_global_load_lds(
        (const __attribute__((address_space(1))) unsigned int*)g,
        (__attribute__((address_space(3))) unsigned int*)l, 16, 0, 0);
}

// Fold BN into weights. Layout = WAVE-PRIVATE per-step slices:
// Wf[s(24)][nb(4)][kc(4)][n64(64)][j(8)] fp16, where s = layer*8+kk,
// k = kk*32 + kc*8 + j, n = nb*64 + n64. Each (s,nb) slice is 4KB contiguous
// = exactly what wave nb consumes at step s (its 64 cols x 32 k).
__global__ void prep_kernel(const float* __restrict__ W0, const float* __restrict__ b0,
                            const float* __restrict__ g0, const float* __restrict__ beta0,
                            const float* __restrict__ m0, const float* __restrict__ v0,
                            const float* __restrict__ Ws, const float* __restrict__ bs,
                            const float* __restrict__ gs, const float* __restrict__ betas,
                            const float* __restrict__ ms, const float* __restrict__ vs,
                            unsigned short* __restrict__ Wf, float* __restrict__ biasArr) {
    int b = blockIdx.x;
    int layer = b >> 8;
    int n = b & 255;
    int k = threadIdx.x;
    const float *W, *bb, *g, *be, *m, *v;
    if (layer == 0) { W = W0; bb = b0; g = g0; be = beta0; m = m0; v = v0; }
    else {
        int i = layer - 1;
        W = Ws + (size_t)i * HF * HF; bb = bs + i * HF; g = gs + i * HF;
        be = betas + i * HF; m = ms + i * HF; v = vs + i * HF;
    }
    float s = g[n] * rsqrtf(v[n] + BN_EPS);
    int kk = k >> 5, kc = (k >> 3) & 3, j = k & 7;
    int sIdx = layer * 8 + kk, nb = n >> 6, n64 = n & 63;
    Wf[((((size_t)sIdx * 4 + nb) * 4 + kc) * 64 + n64) * 8 + j] =
        (unsigned short)f2h(W[n * HF + k] * s);
    if (k == 0) biasArr[layer * HF + n] = (bb[n] - m[n]) * s + be[n];
}

__global__ void count_kernel(const int* __restrict__ dstI, int* __restrict__ cnt, int E) {
    int i = blockIdx.x * 256 + threadIdx.x;
    if (i < E) atomicAdd(cnt + dstI[i], 1);
}

// 3-phase parallel exclusive scan of cnt -> wrk; ALSO overwrites cnt[i] with
// float 1/max(cnt,1) (the mean divisor, consumed by the fused epilogue).
__global__ void scan_local(int* __restrict__ cnt, int* __restrict__ wrk,
                           int* __restrict__ btot, int n) {
    __shared__ int s[1024];
    int b = blockIdx.x, t = threadIdx.x, i = b * 1024 + t;
    int v = (i < n) ? cnt[i] : 0;
    s[t] = v;
    __syncthreads();
#pragma unroll
    for (int d = 1; d < 1024; d <<= 1) {
        int add = (t >= d) ? s[t - d] : 0;
        __syncthreads();
        s[t] += add;
        __syncthreads();
    }
    if (i < n) {
        wrk[i] = s[t] - v;
        ((float*)cnt)[i] = 1.f / fmaxf((float)v, 1.f);   // inv-count, in place
    }
    if (t == 1023) btot[b] = s[1023];
}
__global__ void scan_tops(int* __restrict__ btot, int nb) {
    if (threadIdx.x == 0) {
        int run = 0;
        for (int i = 0; i < nb; ++i) { int v = btot[i]; btot[i] = run; run += v; }
    }
}
__global__ void scan_add(int* __restrict__ wrk, const int* __restrict__ btot, int n) {
    int i = blockIdx.x * 1024 + threadIdx.x;
    if (i < n) wrk[i] += btot[blockIdx.x];
}

// perm[pos] = original edge id, grouped by dst (counting sort)
__global__ void scatter_kernel(const int* __restrict__ dstI, int* __restrict__ wrk,
                               int* __restrict__ perm, int E) {
    int i = blockIdx.x * 256 + threadIdx.x;
    if (i < E) {
        int p = atomicAdd(wrk + dstI[i], 1);
        perm[p] = i;
    }
}

// Fused 3-layer edge MLP over DST-SORTED edges. Block = 64 sorted edges x all
// 256 cols; 256 thr = 4 waves; wave = 64 rows x its 64-col slab.
// LDS 48KB -> 3 blocks/CU. A_act 32KB @0 (swizzled, resident across layers);
// B 16KB @32768 split into 4 WAVE-PRIVATE 4KB slices (wave w owns
// [w*4096, w*4096+4096): its 64 cols x 32 k, layout [kc][n64][16B]).
// BARRIER-FREE K-LOOP: B has no cross-wave dependency, so each wave
// {vmcnt(0) own stage; read own bf; lgkmcnt(0); issue own stage(s+1);
//  af-prefetch; 16 MFMA} and free-runs across the whole layer. Barriers only
// at layer handoffs (A_act rewrite) and epilogue entry (~13/block vs ~52).
// Layers 1-2 swapped operands -> pkrtz handoff. Epilogue: per 16-row round,
// stage vals in LDS; h to ORIGINAL edge slots (full 1KB rows); agg =
// segment-sum over sorted dst runs flushed pre-scaled by inv-count.
__global__ __launch_bounds__(256, 3)
void fused_kernel(const float* __restrict__ x,
                  const int* __restrict__ dstI, const int* __restrict__ srcI,
                  const int* __restrict__ perm,
                  const unsigned char* __restrict__ Wfb,
                  const float* __restrict__ biasArr,
                  const float* __restrict__ invA,
                  unsigned char* __restrict__ hB, float* __restrict__ agg) {
    __shared__ __align__(16) unsigned char lds[49152];
    __shared__ int peL[64];   // original edge id per sorted row
    __shared__ int pdL[64];   // dst per sorted row

    const int base = blockIdx.x * 64;
    const int t = threadIdx.x;
    const int lane = t & 63;
    const int w = t >> 6;           // 0..3 : 64-col slab
    const int lrow = lane & 15;
    const int lgrp = lane >> 4;
    unsigned char* mySlice = lds + 32768 + w * 4096;   // wave-private B slice

    // stage wave-own 4KB slice of global step s: 4 gld_lds16, no cross-wave dep
    auto stageB = [&](int s) {
        const unsigned char* src = Wfb + ((size_t)s << 14) + (w << 12);
#pragma unroll
        for (int i = 0; i < 4; ++i)
            gld_lds16(src + (i * 64 + lane) * 16, mySlice + i * 1024);
    };
    // af fragment read (A_act, swizzled); valid any time A_act is stable
    auto readA = [&](int kk, int mi) -> half8 {
        int row = mi * 16 + lrow;
        return *(const half8*)&lds[row * 512 +
            ((kk * 64 + lgrp * 16) ^ ((row & 7) << 4))];
    };

    stageB(0);   // prologue stage overlaps the gather below

    // ---- layer-1 A fill: gather x via perm (sorted: dst shared within block) ----
    {
        int r = t >> 2, q = t & 3;                 // sorted row, col-quarter
        int e = perm[base + r];
        int idx = (q < 2 ? dstI : srcI)[e];
        const float* xr = x + (size_t)idx * IN_F + (q & 1) * 64;
        int swz = (r & 7) << 4;
#pragma unroll
        for (int u = 0; u < 16; ++u) {
            f32x4 v = *(const f32x4*)(xr + u * 4);
            u32x2 hv = {pk2h(v[0], v[1]), pk2h(v[2], v[3])};
            *(u32x2*)&lds[r * 512 + ((q * 128 + u * 8) ^ swz)] = hv;
        }
    }
    __syncthreads();   // A_act visible to all waves (also drains stage(0))

    f32x4 acc[4][4];
    const f32x4 zero = {0.f, 0.f, 0.f, 0.f};

#pragma unroll
    for (int L = 0; L < 3; ++L) {
#pragma unroll
        for (int mi = 0; mi < 4; ++mi)
#pragma unroll
            for (int ni = 0; ni < 4; ++ni) acc[mi][ni] = zero;

        half8 af_c[4], af_n[4];
#pragma unroll
        for (int kk = 0; kk < 8; ++kk) {
            const int s = L * 8 + kk;

            // wave-local: my stage(s) landed (per-wave vmcnt, no barrier)
            asm volatile("s_waitcnt vmcnt(0)" ::: "memory");
            __builtin_amdgcn_sched_barrier(0);

            if (kk == 0) {
#pragma unroll
                for (int mi = 0; mi < 4; ++mi) af_c[mi] = readA(0, mi);
            }
            half8 bf[4];
#pragma unroll
            for (int ni = 0; ni < 4; ++ni)
                bf[ni] = *(const half8*)&mySlice[lgrp * 1024 + (ni * 16 + lrow) * 16];
            // my LDS reads retired -> safe to overwrite my slice
            asm volatile("s_waitcnt lgkmcnt(0)" ::: "memory");
            __builtin_amdgcn_sched_barrier(0);

            if (s + 1 < 24) stageB(s + 1);   // own slice; lands during MFMA (+handoff)

            if (kk < 7) {      // prefetch next step's af under the MFMA cluster
#pragma unroll
                for (int mi = 0; mi < 4; ++mi) af_n[mi] = readA(kk + 1, mi);
            }

            if (L < 2) {
#pragma unroll
                for (int mi = 0; mi < 4; ++mi)
#pragma unroll
                    for (int ni = 0; ni < 4; ++ni)
                        acc[mi][ni] = __builtin_amdgcn_mfma_f32_16x16x32_f16(
                            bf[ni], af_c[mi], acc[mi][ni], 0, 0, 0);
            } else {
#pragma unroll
                for (int mi = 0; mi < 4; ++mi)
#pragma unroll
                    for (int ni = 0; ni < 4; ++ni)
                        acc[mi][ni] = __builtin_amdgcn_mfma_f32_16x16x32_f16(
                            af_c[mi], bf[ni], acc[mi][ni], 0, 0, 0);
            }
            if (kk < 7) {
#pragma unroll
                for (int mi = 0; mi < 4; ++mi) af_c[mi] = af_n[mi];
            }
        }

        if (L < 2) {
            // ---- handoff (swapped layout): lane&15=edge, reg-dim=col ----
            __syncthreads();   // ALL waves done reading A_act this layer
#pragma unroll
            for (int ni = 0; ni < 4; ++ni) {
                f32x4 bv = *(const f32x4*)(biasArr + L * HF + w * 64 + ni * 16 + lgrp * 4);
#pragma unroll
                for (int mi = 0; mi < 4; ++mi) {
                    int row = mi * 16 + lrow;
                    float v0 = selu_f(acc[mi][ni][0] + bv[0]);
                    float v1 = selu_f(acc[mi][ni][1] + bv[1]);
                    float v2 = selu_f(acc[mi][ni][2] + bv[2]);
                    float v3 = selu_f(acc[mi][ni][3] + bv[3]);
                    u32x2 d = {pk2h(v0, v1), pk2h(v2, v3)};
                    *(u32x2*)&lds[row * 512 +
                        ((w * 128 + ni * 32 + lgrp * 8) ^ ((row & 7) << 4))] = d;
                }
            }
            __syncthreads();   // A_act(L+1) visible before next layer's af reads
        } else {
            // ---- epilogue: all waves past their B-slice reads + A_act reads ----
            __syncthreads();
            if (t < 64) {                     // sorted-row metadata for this block
                int e = perm[base + t];
                peL[t] = e;
                pdL[t] = dstI[e];
            }
            float bc[4];
#pragma unroll
            for (int ni = 0; ni < 4; ++ni) bc[ni] = biasArr[2 * HF + w * 64 + ni * 16 + lrow];
            unsigned char* EP = lds + 32768;
            int curD = -1;
            float carry = 0.f;                // per-column (t) running segment sum
#pragma unroll
            for (int cc = 0; cc < 4; ++cc) {
                if (cc) __syncthreads();
#pragma unroll
                for (int ni = 0; ni < 4; ++ni)
#pragma unroll
                    for (int r = 0; r < 4; ++r) {
                        int er = lgrp * 4 + r;             // row within round 0..15
                        int cg = w * 64 + ni * 16 + lrow;
                        float val = selu_f(acc[cc][ni][r] + bc[ni]);
                        *(float*)&EP[er * 1024 + ((cg * 4) ^ ((er & 7) << 4))] = val;
                    }
                __syncthreads();              // EP + peL/pdL visible
                // h rows -> original edge slots (full 1KB rows, coalesced)
#pragma unroll
                for (int i = 0; i < 4; ++i) {
                    int f = t + i * 256;                  // 1024 x 16B = 16 rows x 64
                    int row = f >> 6, ch = f & 63;
                    f32x4 v = *(const f32x4*)&EP[row * 1024 + ((ch * 16) ^ ((row & 7) << 4))];
                    *(f32x4*)(hB + (size_t)peL[cc * 16 + row] * 1024 + ch * 16) = v;
                }
                // segment sum: thread t = column t, walk the 16 sorted rows
#pragma unroll
                for (int r = 0; r < 16; ++r) {
                    float v = *(const float*)&EP[r * 1024 + ((t * 4) ^ ((r & 7) << 4))];
                    int d = pdL[cc * 16 + r];
                    if (d != curD) {
                        if (curD >= 0)
                            atomicAdd(agg + (size_t)curD * HF + t, carry * invA[curD]);
                        carry = 0.f;
                        curD = d;
                    }
                    carry += v;
                }
            }
            atomicAdd(agg + (size_t)curD * HF + t, carry * invA[curD]);  // flush last
        }
    }
}

extern "C" void kernel_launch(void* const* d_in, const int* in_sizes, int n_in,
                              void* d_out, int out_size, void* d_ws, size_t ws_size,
                              hipStream_t stream) {
    const float* x     = (const float*)d_in[0];
    const int*   ei    = (const int*)d_in[1];
    const float* W0    = (const float*)d_in[2];
    const float* b0    = (const float*)d_in[3];
    const float* g0    = (const float*)d_in[4];
    const float* beta0 = (const float*)d_in[5];
    const float* m0    = (const float*)d_in[6];
    const float* v0    = (const float*)d_in[7];
    const float* Ws    = (const float*)d_in[8];
    const float* bs    = (const float*)d_in[9];
    const float* gs    = (const float*)d_in[10];
    const float* betas = (const float*)d_in[11];
    const float* ms    = (const float*)d_in[12];
    const float* vs    = (const float*)d_in[13];

    const int Nn = in_sizes[0] / IN_F;   // 20000
    const int E  = in_sizes[1] / 2;      // 320000

    float* agg  = (float*)d_out;
    float* hptr = agg + (size_t)Nn * HF;   // final h region of d_out

    // ws layout (byte offsets): Wf 384KB | bias 3KB | cnt/inv 80KB | wrk 80KB | perm 1.25MB
    char* wsb = (char*)d_ws;
    unsigned short* Wf = (unsigned short*)wsb;                      // 393216 B
    float* biasArr = (float*)(wsb + 393216);                        // 3072 B
    int* cnt  = (int*)(wsb + 396288);                               // 80000 B (becomes inv f32)
    int* wrk  = (int*)(wsb + 476288);                               // 80000 B
    int* perm = (int*)(wsb + 556288);                               // 1280000 B
    int* btot = (int*)agg;            // scratch: agg region, re-zeroed below

    const int* srcI = ei;        // edge_index[0]
    const int* dstI = ei + E;    // edge_index[1]

    const int nScan = (Nn + 1023) / 1024;   // 20

    prep_kernel<<<3 * HF, HF, 0, stream>>>(W0, b0, g0, beta0, m0, v0,
                                           Ws, bs, gs, betas, ms, vs, Wf, biasArr);
    hipMemsetAsync(cnt, 0, (size_t)Nn * sizeof(int), stream);
    count_kernel<<<(E + 255) / 256, 256, 0, stream>>>(dstI, cnt, E);
    scan_local<<<nScan, 1024, 0, stream>>>(cnt, wrk, btot, Nn);   // also cnt -> inv
    scan_tops<<<1, 64, 0, stream>>>(btot, nScan);
    scan_add<<<nScan, 1024, 0, stream>>>(wrk, btot, Nn);
    hipMemsetAsync(agg, 0, (size_t)Nn * HF * sizeof(float), stream);  // clears btot too
    scatter_kernel<<<(E + 255) / 256, 256, 0, stream>>>(dstI, wrk, perm, E);

    fused_kernel<<<E / 64, 256, 0, stream>>>(x, dstI, srcI, perm,
                                             (const unsigned char*)Wf, biasArr,
                                             (const float*)cnt,
                                             (unsigned char*)hptr, agg);
}